// Round 10
// baseline (463.267 us; speedup 1.0000x reference)
//
#include <hip/hip_runtime.h>

namespace {

constexpr int N = 20;                  // NEIGHBOR_SIZE
constexpr int ROWS = 5;                // rows per lane
constexpr int GROUPS = 16;             // 4-lane quads per wave = 16 matrices/batch
constexpr int TILE = 2;                // 2 batches/wave, software-pipelined
constexpr int WAVES_PER_BLOCK = 4;     // 256 threads
constexpr int MATS_PER_WAVE = GROUPS * TILE;                     // 32
constexpr int MATS_PER_BLOCK = MATS_PER_WAVE * WAVES_PER_BLOCK;  // 128
constexpr float SIGMA_SQ = 1.0f;
constexpr float PHI = 0.5f;
constexpr float TAU = 0.1f;
// exp(-phi*d) = 2^(-phi*log2(e)*d): pre-scale coords by C = phi*log2(e).
constexpr float CSCALE = 0.72134752f;  // PHI * log2(e)

// Broadcast lane SRC of each 4-lane quad to all 4 lanes: DPP quad_perm.
template <int SRC>
__device__ __forceinline__ float qbcast(float x) {
  constexpr int CTRL = SRC * 0x55;     // quad_perm:[SRC,SRC,SRC,SRC]
  return __builtin_bit_cast(
      float, __builtin_amdgcn_mov_dpp(__builtin_bit_cast(int, x), CTRL, 0xF,
                                      0xF, true));
}

// One Gauss-Jordan elimination step; K is a template parameter so every
// array index is compile-time regardless of unroll heuristics (rule #20).
template <int K>
__device__ __forceinline__ void gj_step(float (&a)[ROWS][N], int o,
                                        const float (&ofl)[4]) {
  constexpr int KO = K / ROWS;         // owner lane of row K
  constexpr int KR = K % ROWS;         // owner-local row index
  float r[N];
#pragma unroll
  for (int j = 0; j < N; ++j) r[j] = qbcast<KO>(a[KR][j]);
  const float ip = __builtin_amdgcn_rcpf(r[K]);
  const float fpiv = 1.0f - ip;
#pragma unroll
  for (int rr = 0; rr < ROWS; ++rr) {
    float f = a[rr][K] * ip;
    if (rr == KR) f = (o == KO) ? fpiv : f;  // one cndmask, only on row KR
    const float nf = -f;
#pragma unroll
    for (int j = 0; j < N; ++j) {
      if (j == K) continue;
      a[rr][j] = __builtin_fmaf(nf, r[j], a[rr][j]);
    }
    a[rr][K] = nf;                     // column K: -A[i][K]/p
  }
  a[KR][K] += ofl[KO];                 // owner diag: (1/p - 1) + 1 = 1/p
}

// Load + pre-scale the 20 points of matrix pm into registers.
__device__ __forceinline__ void load_pts(float (&px)[N], float (&py)[N],
                                         const float* __restrict__ pm) {
  const float4* pv = (const float4*)pm;
#pragma unroll
  for (int q = 0; q < N / 2; ++q) {
    const float4 p = pv[q];
    px[2 * q]     = p.x * CSCALE; py[2 * q]     = p.y * CSCALE;
    px[2 * q + 1] = p.z * CSCALE; py[2 * q + 1] = p.w * CSCALE;
  }
}

// Build my 5 rows of cov from px/py. Row coords come from px/py via
// compile-time-indexed cndmask selects on o (NO memory ops -> the build has
// zero VMEM dependencies, which is what lets it overlap prior stores).
__device__ __forceinline__ void build_cov(float (&a)[ROWS][N],
                                          const float (&px)[N],
                                          const float (&py)[N], int o,
                                          const float (&tdiag)[4]) {
  float myx[ROWS], myy[ROWS];
#pragma unroll
  for (int rr = 0; rr < ROWS; ++rr) {
    myx[rr] = o == 3 ? px[15 + rr]
            : o == 2 ? px[10 + rr]
            : o == 1 ? px[5 + rr] : px[rr];
    myy[rr] = o == 3 ? py[15 + rr]
            : o == 2 ? py[10 + rr]
            : o == 1 ? py[5 + rr] : py[rr];
  }
#pragma unroll
  for (int rr = 0; rr < ROWS; ++rr) {
#pragma unroll
    for (int c = 0; c < N; ++c) {
      const float dx = px[c] - myx[rr];
      const float dy = py[c] - myy[rr];
      const float d  = __builtin_amdgcn_sqrtf(__builtin_fmaf(dx, dx, dy * dy));
      float v = SIGMA_SQ * __builtin_amdgcn_exp2f(-d);  // neg -> input mod
      if (c % ROWS == rr) v += tdiag[c / ROWS];
      a[rr][c] = v;
    }
  }
}

__device__ __forceinline__ void gj_all(float (&a)[ROWS][N], int o,
                                       const float (&ofl)[4]) {
  gj_step<0>(a, o, ofl);  gj_step<1>(a, o, ofl);  gj_step<2>(a, o, ofl);
  gj_step<3>(a, o, ofl);  gj_step<4>(a, o, ofl);  gj_step<5>(a, o, ofl);
  gj_step<6>(a, o, ofl);  gj_step<7>(a, o, ofl);  gj_step<8>(a, o, ofl);
  gj_step<9>(a, o, ofl);  gj_step<10>(a, o, ofl); gj_step<11>(a, o, ofl);
  gj_step<12>(a, o, ofl); gj_step<13>(a, o, ofl); gj_step<14>(a, o, ofl);
  gj_step<15>(a, o, ofl); gj_step<16>(a, o, ofl); gj_step<17>(a, o, ofl);
  gj_step<18>(a, o, ofl); gj_step<19>(a, o, ofl);
}

// Stage pass p (4 matrices) into wbuf. Only the 16 owning lanes write.
__device__ __forceinline__ void stage_pass(float* wbuf, const float (&a)[ROWS][N],
                                           int g, int o, int p) {
  if ((g >> 2) == p) {
    float* dst = wbuf + (g & 3) * (N * N) + o * (ROWS * N);
#pragma unroll
    for (int rr = 0; rr < ROWS; ++rr) {
#pragma unroll
      for (int q = 0; q < N / 4; ++q) {
        *(float4*)&dst[rr * N + 4 * q] =
            make_float4(a[rr][4 * q], a[rr][4 * q + 1], a[rr][4 * q + 2],
                        a[rr][4 * q + 3]);
      }
    }
  }
}

// Read 6.4 KB back densely and store (1 KB per wave-instruction).
__device__ __forceinline__ void readout_pass(const float* wbuf,
                                             float* __restrict__ gout,
                                             int lane) {
#pragma unroll
  for (int s = 0; s < 6; ++s) {
    const float4 v = *(const float4*)&wbuf[lane * 4 + s * 256];
    *(float4*)&gout[lane * 4 + s * 256] = v;
  }
  if (lane < 16) {
    const float4 v = *(const float4*)&wbuf[lane * 4 + 6 * 256];
    *(float4*)&gout[lane * 4 + 6 * 256] = v;
  }
}

#define LGKM_FENCE() asm volatile("s_waitcnt lgkmcnt(0)" ::: "memory")

// Full 4-pass dense epilogue for one batch.
__device__ __forceinline__ void epilogue(float* wbuf, const float (&a)[ROWS][N],
                                         float* __restrict__ out, int mbase,
                                         int g, int o, int lane) {
#pragma unroll
  for (int p = 0; p < 4; ++p) {
    stage_pass(wbuf, a, g, o, p);
    LGKM_FENCE();
    readout_pass(wbuf, out + (size_t)(mbase + 4 * p) * (N * N), lane);
    LGKM_FENCE();  // reads must land before next pass overwrites the buffer
  }
}

__global__ __launch_bounds__(256, 4) void invcov_kernel(
    const float* __restrict__ pos, float* __restrict__ out, int B) {
  __shared__ float lds[WAVES_PER_BLOCK][4 * N * N];

  const int tid  = threadIdx.x;
  const int lane = tid & 63;
  const int wave = tid >> 6;
  const int g    = lane >> 2;          // quad = matrix within batch, 0..15
  const int o    = lane & 3;           // lane within quad, owns rows 5o..5o+4
  const int wbase  = blockIdx.x * MATS_PER_BLOCK + wave * MATS_PER_WAVE;
  const int mbase0 = wbase;
  const int mbase1 = wbase + GROUPS;
  float* wbuf = &lds[wave][0];

  // Per-quad-lane constant masks, constant-indexed (batch-invariant).
  float tdiag[4], ofl[4];
#pragma unroll
  for (int t = 0; t < 4; ++t) {
    const bool is = (o == t);
    tdiag[t] = is ? (TAU * SIGMA_SQ) : 0.0f;
    ofl[t]   = is ? 1.0f : 0.0f;
  }

  const int m0  = mbase0 + g;
  const int mc0 = (m0 < B) ? m0 : (B - 1);
  const int m1  = mbase1 + g;
  const int mc1 = (m1 < B) ? m1 : (B - 1);

  // ---- batch 0: load -> build -> GJ ----
  float px[N], py[N];
  load_pts(px, py, pos + (size_t)mc0 * (2 * N));
  float a[ROWS][N];
  build_cov(a, px, py, o, tdiag);
  gj_all(a, o, ofl);

  // ---- software pipeline point: issue batch 1's loads BEFORE any of
  // batch 0's global stores enter the (in-order) vmcnt queue. sched_barrier
  // pins them here: not hoisted into GJ0 (VGPR peak), not sunk below stores.
  __builtin_amdgcn_sched_barrier(0);
  float px1[N], py1[N];
  load_pts(px1, py1, pos + (size_t)mc1 * (2 * N));
  __builtin_amdgcn_sched_barrier(0);

  // ---- batch 0 epilogue: 25.6 KB of stores, fire-and-forget; they drain
  // under batch 1's (VMEM-free) build+GJ below.
  if (mbase0 + GROUPS <= B) {
    epilogue(wbuf, a, out, mbase0, g, o, lane);
  }

  // ---- batch 1: build (no VMEM deps: waits only on its own px1/py1 loads,
  // which precede the stores in vmcnt order) -> GJ -> epilogue.
  build_cov(a, px1, py1, o, tdiag);
  gj_all(a, o, ofl);
  if (mbase1 + GROUPS <= B) {
    epilogue(wbuf, a, out, mbase1, g, o, lane);
  }
  // B % 16 == 0 for the bench shape, so batches are either fully in-bounds
  // (handled above) or fully out-of-bounds (skipped; loads were clamped).
}

}  // namespace

extern "C" void kernel_launch(void* const* d_in, const int* in_sizes, int n_in,
                              void* d_out, int out_size, void* d_ws, size_t ws_size,
                              hipStream_t stream) {
  const float* pos = (const float*)d_in[0];   // [B, 40] f32
  // d_in[1] (edge_list, int64) is unused by the reference computation.
  float* out = (float*)d_out;                 // [B, 20, 20] f32
  const int B = in_sizes[0] / (2 * N);
  const int blocks = (B + MATS_PER_BLOCK - 1) / MATS_PER_BLOCK;
  invcov_kernel<<<blocks, 256, 0, stream>>>(pos, out, B);
}

// Round 11
// 141.066 us; speedup vs baseline: 3.2840x; 3.2840x over previous
//
#include <hip/hip_runtime.h>

namespace {

constexpr int N = 20;                  // NEIGHBOR_SIZE
constexpr int ROWS = 5;                // rows per lane
constexpr int GROUPS = 16;             // 4-lane quads per wave = 16 matrices/batch
constexpr int TILE = 2;                // 2 batches/wave, software-pipelined
constexpr int WAVES_PER_BLOCK = 4;     // 256 threads
constexpr int MATS_PER_WAVE = GROUPS * TILE;                     // 32
constexpr int MATS_PER_BLOCK = MATS_PER_WAVE * WAVES_PER_BLOCK;  // 128 -> 1563 blocks
constexpr float SIGMA_SQ = 1.0f;
constexpr float PHI = 0.5f;
constexpr float TAU = 0.1f;
// exp(-phi*d) = 2^(-phi*log2(e)*d): pre-scale coords by C = phi*log2(e).
constexpr float CSCALE = 0.72134752f;  // PHI * log2(e)

// Broadcast lane SRC of each 4-lane quad to all 4 lanes: DPP quad_perm.
template <int SRC>
__device__ __forceinline__ float qbcast(float x) {
  constexpr int CTRL = SRC * 0x55;     // quad_perm:[SRC,SRC,SRC,SRC]
  return __builtin_bit_cast(
      float, __builtin_amdgcn_mov_dpp(__builtin_bit_cast(int, x), CTRL, 0xF,
                                      0xF, true));
}

// One Gauss-Jordan elimination step; K is a template parameter so every
// array index is compile-time regardless of unroll heuristics (rule #20).
template <int K>
__device__ __forceinline__ void gj_step(float (&a)[ROWS][N], int o,
                                        const float (&ofl)[4]) {
  constexpr int KO = K / ROWS;         // owner lane of row K
  constexpr int KR = K % ROWS;         // owner-local row index
  float r[N];
#pragma unroll
  for (int j = 0; j < N; ++j) r[j] = qbcast<KO>(a[KR][j]);
  const float ip = __builtin_amdgcn_rcpf(r[K]);
  const float fpiv = 1.0f - ip;
#pragma unroll
  for (int rr = 0; rr < ROWS; ++rr) {
    float f = a[rr][K] * ip;
    if (rr == KR) f = (o == KO) ? fpiv : f;  // one cndmask, only on row KR
    const float nf = -f;
#pragma unroll
    for (int j = 0; j < N; ++j) {
      if (j == K) continue;
      a[rr][j] = __builtin_fmaf(nf, r[j], a[rr][j]);
    }
    a[rr][K] = nf;                     // column K: -A[i][K]/p
  }
  a[KR][K] += ofl[KO];                 // owner diag: (1/p - 1) + 1 = 1/p
}

// Load + pre-scale the 20 points of matrix pm into registers.
__device__ __forceinline__ void load_pts(float (&px)[N], float (&py)[N],
                                         const float* __restrict__ pm) {
  const float4* pv = (const float4*)pm;
#pragma unroll
  for (int q = 0; q < N / 2; ++q) {
    const float4 p = pv[q];
    px[2 * q]     = p.x * CSCALE; py[2 * q]     = p.y * CSCALE;
    px[2 * q + 1] = p.z * CSCALE; py[2 * q + 1] = p.w * CSCALE;
  }
}

// Build my 5 rows of cov from px/py. Row coords come from px/py via
// compile-time-indexed cndmask selects on o (NO memory ops -> the build has
// zero VMEM dependencies, which is what lets it overlap prior stores).
__device__ __forceinline__ void build_cov(float (&a)[ROWS][N],
                                          const float (&px)[N],
                                          const float (&py)[N], int o,
                                          const float (&tdiag)[4]) {
  float myx[ROWS], myy[ROWS];
#pragma unroll
  for (int rr = 0; rr < ROWS; ++rr) {
    myx[rr] = o == 3 ? px[15 + rr]
            : o == 2 ? px[10 + rr]
            : o == 1 ? px[5 + rr] : px[rr];
    myy[rr] = o == 3 ? py[15 + rr]
            : o == 2 ? py[10 + rr]
            : o == 1 ? py[5 + rr] : py[rr];
  }
#pragma unroll
  for (int rr = 0; rr < ROWS; ++rr) {
#pragma unroll
    for (int c = 0; c < N; ++c) {
      const float dx = px[c] - myx[rr];
      const float dy = py[c] - myy[rr];
      const float d  = __builtin_amdgcn_sqrtf(__builtin_fmaf(dx, dx, dy * dy));
      float v = SIGMA_SQ * __builtin_amdgcn_exp2f(-d);  // neg -> input mod
      if (c % ROWS == rr) v += tdiag[c / ROWS];
      a[rr][c] = v;
    }
  }
}

__device__ __forceinline__ void gj_all(float (&a)[ROWS][N], int o,
                                       const float (&ofl)[4]) {
  gj_step<0>(a, o, ofl);  gj_step<1>(a, o, ofl);  gj_step<2>(a, o, ofl);
  gj_step<3>(a, o, ofl);  gj_step<4>(a, o, ofl);  gj_step<5>(a, o, ofl);
  gj_step<6>(a, o, ofl);  gj_step<7>(a, o, ofl);  gj_step<8>(a, o, ofl);
  gj_step<9>(a, o, ofl);  gj_step<10>(a, o, ofl); gj_step<11>(a, o, ofl);
  gj_step<12>(a, o, ofl); gj_step<13>(a, o, ofl); gj_step<14>(a, o, ofl);
  gj_step<15>(a, o, ofl); gj_step<16>(a, o, ofl); gj_step<17>(a, o, ofl);
  gj_step<18>(a, o, ofl); gj_step<19>(a, o, ofl);
}

// Stage pass p (4 matrices) into wbuf. Only the 16 owning lanes write.
__device__ __forceinline__ void stage_pass(float* wbuf, const float (&a)[ROWS][N],
                                           int g, int o, int p) {
  if ((g >> 2) == p) {
    float* dst = wbuf + (g & 3) * (N * N) + o * (ROWS * N);
#pragma unroll
    for (int rr = 0; rr < ROWS; ++rr) {
#pragma unroll
      for (int q = 0; q < N / 4; ++q) {
        *(float4*)&dst[rr * N + 4 * q] =
            make_float4(a[rr][4 * q], a[rr][4 * q + 1], a[rr][4 * q + 2],
                        a[rr][4 * q + 3]);
      }
    }
  }
}

// Read 6.4 KB back densely and store (1 KB per wave-instruction).
__device__ __forceinline__ void readout_pass(const float* wbuf,
                                             float* __restrict__ gout,
                                             int lane) {
#pragma unroll
  for (int s = 0; s < 6; ++s) {
    const float4 v = *(const float4*)&wbuf[lane * 4 + s * 256];
    *(float4*)&gout[lane * 4 + s * 256] = v;
  }
  if (lane < 16) {
    const float4 v = *(const float4*)&wbuf[lane * 4 + 6 * 256];
    *(float4*)&gout[lane * 4 + 6 * 256] = v;
  }
}

#define LGKM_FENCE() asm volatile("s_waitcnt lgkmcnt(0)" ::: "memory")

// Full 4-pass dense epilogue for one batch.
__device__ __forceinline__ void epilogue(float* wbuf, const float (&a)[ROWS][N],
                                         float* __restrict__ out, int mbase,
                                         int g, int o, int lane) {
#pragma unroll
  for (int p = 0; p < 4; ++p) {
    stage_pass(wbuf, a, g, o, p);
    LGKM_FENCE();
    readout_pass(wbuf, out + (size_t)(mbase + 4 * p) * (N * N), lane);
    LGKM_FENCE();  // reads must land before next pass overwrites the buffer
  }
}

// launch_bounds(256, 2): VGPR cap 256. R10 lesson: capping at 128 with the
// pipeline's ~160 live regs caused a catastrophic spill (FETCH 468 MB).
__global__ __launch_bounds__(256, 2) void invcov_kernel(
    const float* __restrict__ pos, float* __restrict__ out, int B) {
  __shared__ float lds[WAVES_PER_BLOCK][4 * N * N];

  const int tid  = threadIdx.x;
  const int lane = tid & 63;
  const int wave = tid >> 6;
  const int g    = lane >> 2;          // quad = matrix within batch, 0..15
  const int o    = lane & 3;           // lane within quad, owns rows 5o..5o+4
  const int wbase  = blockIdx.x * MATS_PER_BLOCK + wave * MATS_PER_WAVE;
  const int mbase0 = wbase;
  const int mbase1 = wbase + GROUPS;
  float* wbuf = &lds[wave][0];

  // Per-quad-lane constant masks, constant-indexed (batch-invariant).
  float tdiag[4], ofl[4];
#pragma unroll
  for (int t = 0; t < 4; ++t) {
    const bool is = (o == t);
    tdiag[t] = is ? (TAU * SIGMA_SQ) : 0.0f;
    ofl[t]   = is ? 1.0f : 0.0f;
  }

  const int m0  = mbase0 + g;
  const int mc0 = (m0 < B) ? m0 : (B - 1);
  const int m1  = mbase1 + g;
  const int mc1 = (m1 < B) ? m1 : (B - 1);

  // ---- batch 0: load -> build -> GJ ----
  float px[N], py[N];
  load_pts(px, py, pos + (size_t)mc0 * (2 * N));
  float a[ROWS][N];
  build_cov(a, px, py, o, tdiag);
  gj_all(a, o, ofl);

  // ---- software pipeline point: issue batch 1's loads BEFORE any of
  // batch 0's global stores enter the (in-order) vmcnt queue. sched_barrier
  // pins them here: not hoisted into GJ0 (VGPR peak), not sunk below stores.
  __builtin_amdgcn_sched_barrier(0);
  float px1[N], py1[N];
  load_pts(px1, py1, pos + (size_t)mc1 * (2 * N));
  __builtin_amdgcn_sched_barrier(0);

  // ---- batch 0 epilogue: 25.6 KB of stores, fire-and-forget; they drain
  // under batch 1's (VMEM-free) build+GJ below.
  if (mbase0 + GROUPS <= B) {
    epilogue(wbuf, a, out, mbase0, g, o, lane);
  }

  // ---- batch 1: build (waits only on its own px1/py1 loads, which precede
  // the stores in vmcnt order -> counted wait, stores keep draining) -> GJ.
  build_cov(a, px1, py1, o, tdiag);
  gj_all(a, o, ofl);
  if (mbase1 + GROUPS <= B) {
    epilogue(wbuf, a, out, mbase1, g, o, lane);
  }
  // B % 16 == 0 for the bench shape, so batches are either fully in-bounds
  // (handled above) or fully out-of-bounds (skipped; loads were clamped).
}

}  // namespace

extern "C" void kernel_launch(void* const* d_in, const int* in_sizes, int n_in,
                              void* d_out, int out_size, void* d_ws, size_t ws_size,
                              hipStream_t stream) {
  const float* pos = (const float*)d_in[0];   // [B, 40] f32
  // d_in[1] (edge_list, int64) is unused by the reference computation.
  float* out = (float*)d_out;                 // [B, 20, 20] f32
  const int B = in_sizes[0] / (2 * N);
  const int blocks = (B + MATS_PER_BLOCK - 1) / MATS_PER_BLOCK;
  invcov_kernel<<<blocks, 256, 0, stream>>>(pos, out, B);
}

// Round 12
// 132.160 us; speedup vs baseline: 3.5054x; 1.0674x over previous
//
#include <hip/hip_runtime.h>

namespace {

constexpr int N = 20;                  // NEIGHBOR_SIZE
constexpr int ROWS = 5;                // rows per lane
constexpr int GROUPS = 16;             // 4-lane quads per wave = 16 matrices/tile
constexpr int WAVES_PER_BLOCK = 4;     // 256 threads
constexpr int NBLOCKS = 1024;          // 4 blocks/CU exactly; persistent waves
constexpr int PTS_FLOATS = GROUPS * 2 * N;   // 640 floats = 2560 B per tile
constexpr int WBUF_FLOATS = 4 * N * N;       // 1600 floats transpose buffer
constexpr float SIGMA_SQ = 1.0f;
constexpr float PHI = 0.5f;
constexpr float TAU = 0.1f;
constexpr float CSCALE = 0.72134752f;  // PHI * log2(e)

#define LGKM_FENCE() asm volatile("s_waitcnt lgkmcnt(0)" ::: "memory")
#define SCHED_FENCE() __builtin_amdgcn_sched_barrier(0)

// Broadcast lane SRC of each 4-lane quad to all 4 lanes: DPP quad_perm.
template <int SRC>
__device__ __forceinline__ float qbcast(float x) {
  constexpr int CTRL = SRC * 0x55;
  return __builtin_bit_cast(
      float, __builtin_amdgcn_mov_dpp(__builtin_bit_cast(int, x), CTRL, 0xF,
                                      0xF, true));
}

// One Gauss-Jordan step; K template => all indices compile-time (rule #20).
template <int K>
__device__ __forceinline__ void gj_step(float (&a)[ROWS][N], int o,
                                        const float (&ofl)[4]) {
  constexpr int KO = K / ROWS;
  constexpr int KR = K % ROWS;
  float r[N];
#pragma unroll
  for (int j = 0; j < N; ++j) r[j] = qbcast<KO>(a[KR][j]);
  const float ip = __builtin_amdgcn_rcpf(r[K]);
  const float fpiv = 1.0f - ip;
#pragma unroll
  for (int rr = 0; rr < ROWS; ++rr) {
    float f = a[rr][K] * ip;
    if (rr == KR) f = (o == KO) ? fpiv : f;
    const float nf = -f;
#pragma unroll
    for (int j = 0; j < N; ++j) {
      if (j == K) continue;
      a[rr][j] = __builtin_fmaf(nf, r[j], a[rr][j]);
    }
    a[rr][K] = nf;
  }
  a[KR][K] += ofl[KO];
}

__device__ __forceinline__ void gj_all(float (&a)[ROWS][N], int o,
                                       const float (&ofl)[4]) {
  gj_step<0>(a, o, ofl);  gj_step<1>(a, o, ofl);  gj_step<2>(a, o, ofl);
  gj_step<3>(a, o, ofl);  gj_step<4>(a, o, ofl);  gj_step<5>(a, o, ofl);
  gj_step<6>(a, o, ofl);  gj_step<7>(a, o, ofl);  gj_step<8>(a, o, ofl);
  gj_step<9>(a, o, ofl);  gj_step<10>(a, o, ofl); gj_step<11>(a, o, ofl);
  gj_step<12>(a, o, ofl); gj_step<13>(a, o, ofl); gj_step<14>(a, o, ofl);
  gj_step<15>(a, o, ofl); gj_step<16>(a, o, ofl); gj_step<17>(a, o, ofl);
  gj_step<18>(a, o, ofl); gj_step<19>(a, o, ofl);
}

// Async-stage one tile (16 matrices, 2560 B) into LDS: 4 global_load_lds ops,
// ZERO VGPRs of state. Dest must be linear base+lane*size (m104).
__device__ __forceinline__ void stage_tile(float* pts,
                                           const float* __restrict__ gsrc,
                                           int lane) {
  __builtin_amdgcn_global_load_lds(
      (const __attribute__((address_space(1))) void*)(gsrc + lane * 4),
      (__attribute__((address_space(3))) void*)(pts), 16, 0, 0);
  __builtin_amdgcn_global_load_lds(
      (const __attribute__((address_space(1))) void*)(gsrc + 256 + lane * 4),
      (__attribute__((address_space(3))) void*)(pts + 256), 16, 0, 0);
  __builtin_amdgcn_global_load_lds(
      (const __attribute__((address_space(1))) void*)(gsrc + 512 + lane),
      (__attribute__((address_space(3))) void*)(pts + 512), 4, 0, 0);
  __builtin_amdgcn_global_load_lds(
      (const __attribute__((address_space(1))) void*)(gsrc + 576 + lane),
      (__attribute__((address_space(3))) void*)(pts + 576), 4, 0, 0);
}

// LDS pts -> registers, pre-scaled (quad-broadcast ds_read_b128 x10).
__device__ __forceinline__ void read_pts(float (&px)[N], float (&py)[N],
                                         const float* pts, int g) {
  const float4* pv = (const float4*)(pts + g * 2 * N);
#pragma unroll
  for (int q = 0; q < N / 2; ++q) {
    const float4 p = pv[q];
    px[2 * q]     = p.x * CSCALE; py[2 * q]     = p.y * CSCALE;
    px[2 * q + 1] = p.z * CSCALE; py[2 * q + 1] = p.w * CSCALE;
  }
}

// Build my 5 rows; row coords via compile-time selects (no memory ops).
__device__ __forceinline__ void build_cov(float (&a)[ROWS][N],
                                          const float (&px)[N],
                                          const float (&py)[N], int o,
                                          const float (&tdiag)[4]) {
  float myx[ROWS], myy[ROWS];
#pragma unroll
  for (int rr = 0; rr < ROWS; ++rr) {
    myx[rr] = o == 3 ? px[15 + rr] : o == 2 ? px[10 + rr]
            : o == 1 ? px[5 + rr]  : px[rr];
    myy[rr] = o == 3 ? py[15 + rr] : o == 2 ? py[10 + rr]
            : o == 1 ? py[5 + rr]  : py[rr];
  }
#pragma unroll
  for (int rr = 0; rr < ROWS; ++rr) {
#pragma unroll
    for (int c = 0; c < N; ++c) {
      const float dx = px[c] - myx[rr];
      const float dy = py[c] - myy[rr];
      const float d  = __builtin_amdgcn_sqrtf(__builtin_fmaf(dx, dx, dy * dy));
      float v = SIGMA_SQ * __builtin_amdgcn_exp2f(-d);
      if (c % ROWS == rr) v += tdiag[c / ROWS];
      a[rr][c] = v;
    }
  }
}

__device__ __forceinline__ void stage_pass(float* wbuf,
                                           const float (&a)[ROWS][N], int g,
                                           int o, int p) {
  if ((g >> 2) == p) {
    float* dst = wbuf + (g & 3) * (N * N) + o * (ROWS * N);
#pragma unroll
    for (int rr = 0; rr < ROWS; ++rr) {
#pragma unroll
      for (int q = 0; q < N / 4; ++q) {
        *(float4*)&dst[rr * N + 4 * q] =
            make_float4(a[rr][4 * q], a[rr][4 * q + 1], a[rr][4 * q + 2],
                        a[rr][4 * q + 3]);
      }
    }
  }
}

__device__ __forceinline__ void readout_pass(const float* wbuf,
                                             float* __restrict__ gout,
                                             int lane) {
#pragma unroll
  for (int s = 0; s < 6; ++s) {
    const float4 v = *(const float4*)&wbuf[lane * 4 + s * 256];
    *(float4*)&gout[lane * 4 + s * 256] = v;
  }
  if (lane < 16) {
    const float4 v = *(const float4*)&wbuf[lane * 4 + 6 * 256];
    *(float4*)&gout[lane * 4 + 6 * 256] = v;
  }
}

// 28 global_store_dwordx4 per wave per tile (4 passes x 7). This count is
// what the loop-top counted vmcnt relies on; over-counting only over-waits.
__device__ __forceinline__ void epilogue(float* wbuf, const float (&a)[ROWS][N],
                                         float* __restrict__ out, int mbase,
                                         int g, int o, int lane) {
#pragma unroll
  for (int p = 0; p < 4; ++p) {
    stage_pass(wbuf, a, g, o, p);
    LGKM_FENCE();
    readout_pass(wbuf, out + (size_t)(mbase + 4 * p) * (N * N), lane);
    LGKM_FENCE();
  }
}

__global__ __launch_bounds__(256, 2) void invcov_kernel(
    const float* __restrict__ pos, float* __restrict__ out, int B) {
  __shared__ float lds[WAVES_PER_BLOCK][PTS_FLOATS + WBUF_FLOATS];

  const int tid  = threadIdx.x;
  const int lane = tid & 63;
  const int wave = tid >> 6;
  const int g    = lane >> 2;
  const int o    = lane & 3;
  const int wgid   = blockIdx.x * WAVES_PER_BLOCK + wave;
  const int nwaves = gridDim.x * WAVES_PER_BLOCK;
  const int ntiles = B / GROUPS;       // full tiles; remainder handled below
  float* pts  = &lds[wave][0];
  float* wbuf = &lds[wave][PTS_FLOATS];

  float tdiag[4], ofl[4];
#pragma unroll
  for (int t = 0; t < 4; ++t) {
    const bool is = (o == t);
    tdiag[t] = is ? (TAU * SIGMA_SQ) : 0.0f;
    ofl[t]   = is ? 1.0f : 0.0f;
  }

  // Prologue: stage my first tile.
  if (wgid < ntiles) stage_tile(pts, pos + (size_t)wgid * PTS_FLOATS, lane);

#pragma unroll 1
  for (int t = wgid; t < ntiles; t += nwaves) {
    // Counted wait: retire only the 4 glls (oldest). On later iterations the
    // previous tile's 28 stores stay in flight and drain under this tile's
    // compute. In-order vmcnt retirement => "<=28 outstanding" implies the
    // older glls are done; any compiler-added vmem (spill) only over-waits.
    SCHED_FENCE();
    if (t == wgid) {
      asm volatile("s_waitcnt vmcnt(0)" ::: "memory");
    } else {
      asm volatile("s_waitcnt vmcnt(28)" ::: "memory");
    }
    SCHED_FENCE();

    float px[N], py[N];
    read_pts(px, py, pts, g);
    LGKM_FENCE();        // pts consumed into regs; buffer reusable
    SCHED_FENCE();

    const int tn = t + nwaves;
    if (tn < ntiles) stage_tile(pts, pos + (size_t)tn * PTS_FLOATS, lane);
    SCHED_FENCE();       // pin gll issue BEFORE this tile's stores

    float a[ROWS][N];
    build_cov(a, px, py, o, tdiag);
    gj_all(a, o, ofl);

    epilogue(wbuf, a, out, t * GROUPS, g, o, lane);
  }

  // Remainder matrices (B % 16): one wave handles them directly. Not hit for
  // the bench shape (200000 % 16 == 0) but kept for correctness.
  const int rem = B - ntiles * GROUPS;
  if (rem && wgid == 0) {
    const int m  = ntiles * GROUPS + g;
    const int mc = (m < B) ? m : (B - 1);
    float px[N], py[N];
    const float4* pv = (const float4*)(pos + (size_t)mc * (2 * N));
#pragma unroll
    for (int q = 0; q < N / 2; ++q) {
      const float4 p = pv[q];
      px[2 * q]     = p.x * CSCALE; py[2 * q]     = p.y * CSCALE;
      px[2 * q + 1] = p.z * CSCALE; py[2 * q + 1] = p.w * CSCALE;
    }
    float a[ROWS][N];
    build_cov(a, px, py, o, tdiag);
    gj_all(a, o, ofl);
    if (m < B) {
      float* om = out + (size_t)m * (N * N) + (ROWS * o) * N;
#pragma unroll
      for (int rr = 0; rr < ROWS; ++rr) {
#pragma unroll
        for (int q = 0; q < N / 4; ++q) {
          *(float4*)&om[rr * N + 4 * q] =
              make_float4(a[rr][4 * q], a[rr][4 * q + 1], a[rr][4 * q + 2],
                          a[rr][4 * q + 3]);
        }
      }
    }
  }
}

}  // namespace

extern "C" void kernel_launch(void* const* d_in, const int* in_sizes, int n_in,
                              void* d_out, int out_size, void* d_ws, size_t ws_size,
                              hipStream_t stream) {
  const float* pos = (const float*)d_in[0];   // [B, 40] f32
  // d_in[1] (edge_list, int64) is unused by the reference computation.
  float* out = (float*)d_out;                 // [B, 20, 20] f32
  const int B = in_sizes[0] / (2 * N);
  invcov_kernel<<<NBLOCKS, 256, 0, stream>>>(pos, out, B);
}

// Round 13
// 125.102 us; speedup vs baseline: 3.7031x; 1.0564x over previous
//
#include <hip/hip_runtime.h>

namespace {

constexpr int N = 20;                  // NEIGHBOR_SIZE
constexpr int ROWS = 5;                // rows per lane
constexpr int GROUPS = 16;             // 4-lane quads per wave = 16 matrices/wave
constexpr int WAVES_PER_BLOCK = 4;     // 256 threads
constexpr int MATS_PER_BLOCK = GROUPS * WAVES_PER_BLOCK;  // 64 -> 3125 blocks exact
constexpr float SIGMA_SQ = 1.0f;
constexpr float PHI = 0.5f;
constexpr float TAU = 0.1f;
// exp(-phi*d) = 2^(-phi*log2(e)*d): pre-scale coords by C = phi*log2(e); the
// negate folds into the v_exp_f32 input modifier.
constexpr float CSCALE = 0.72134752f;  // PHI * log2(e)

// Broadcast lane SRC of each 4-lane quad to all 4 lanes: DPP quad_perm,
// pure VALU (per-SIMD pipe) -- no LDS traffic.
template <int SRC>
__device__ __forceinline__ float qbcast(float x) {
  constexpr int CTRL = SRC * 0x55;     // quad_perm:[SRC,SRC,SRC,SRC]
  return __builtin_bit_cast(
      float, __builtin_amdgcn_mov_dpp(__builtin_bit_cast(int, x), CTRL, 0xF,
                                      0xF, true));
}

// One Gauss-Jordan elimination step; K is a template parameter so every
// array index is compile-time regardless of unroll heuristics (rule #20).
template <int K>
__device__ __forceinline__ void gj_step(float (&a)[ROWS][N], int o,
                                        const float (&ofl)[4]) {
  constexpr int KO = K / ROWS;         // owner lane of row K
  constexpr int KR = K % ROWS;         // owner-local row index
  float r[N];
#pragma unroll
  for (int j = 0; j < N; ++j) r[j] = qbcast<KO>(a[KR][j]);
  const float ip = __builtin_amdgcn_rcpf(r[K]);
  const float fpiv = 1.0f - ip;
#pragma unroll
  for (int rr = 0; rr < ROWS; ++rr) {
    float f = a[rr][K] * ip;
    if (rr == KR) f = (o == KO) ? fpiv : f;  // one cndmask, only on row KR
    const float nf = -f;
#pragma unroll
    for (int j = 0; j < N; ++j) {
      if (j == K) continue;
      a[rr][j] = __builtin_fmaf(nf, r[j], a[rr][j]);
    }
    a[rr][K] = nf;                     // column K: -A[i][K]/p
  }
  a[KR][K] += ofl[KO];                 // owner diag: (1/p - 1) + 1 = 1/p
}

__global__ __launch_bounds__(256, 2) void invcov_kernel(
    const float* __restrict__ pos, float* __restrict__ out, int B) {
  const int tid  = threadIdx.x;
  const int lane = tid & 63;
  const int wave = tid >> 6;
  const int g    = lane >> 2;          // quad = matrix within wave, 0..15
  const int o    = lane & 3;           // lane within quad, owns rows 5o..5o+4
  const int m    = blockIdx.x * MATS_PER_BLOCK + wave * GROUPS + g;
  const int mc   = (m < B) ? m : (B - 1);

  const float* pm = pos + (size_t)mc * (2 * N);

  // All 20 points in registers, pre-scaled by CSCALE (compile-time indexed).
  float px[N], py[N];
  {
    const float4* pv = (const float4*)pm;
#pragma unroll
    for (int q = 0; q < N / 2; ++q) {
      const float4 p = pv[q];
      px[2 * q]     = p.x * CSCALE; py[2 * q]     = p.y * CSCALE;
      px[2 * q + 1] = p.z * CSCALE; py[2 * q + 1] = p.w * CSCALE;
    }
  }
  // My 5 rows' coords: runtime offset -> tiny L1-hit loads, not reg-indexing.
  float myx[ROWS], myy[ROWS];
  {
    const float2* pm2 = (const float2*)pm;
#pragma unroll
    for (int rr = 0; rr < ROWS; ++rr) {
      const float2 p = pm2[ROWS * o + rr];
      myx[rr] = p.x * CSCALE; myy[rr] = p.y * CSCALE;
    }
  }

  // Per-quad-lane constant masks, constant-indexed.
  float tdiag[4], ofl[4];
#pragma unroll
  for (int t = 0; t < 4; ++t) {
    const bool is = (o == t);
    tdiag[t] = is ? (TAU * SIGMA_SQ) : 0.0f;
    ofl[t]   = is ? 1.0f : 0.0f;
  }

  // Build my 5 rows: a[rr][c] = s^2 * 2^(-C*d) (+ tau*s^2 on my diagonal).
  float a[ROWS][N];
#pragma unroll
  for (int rr = 0; rr < ROWS; ++rr) {
#pragma unroll
    for (int c = 0; c < N; ++c) {
      const float dx = px[c] - myx[rr];
      const float dy = py[c] - myy[rr];
      const float d  = __builtin_amdgcn_sqrtf(__builtin_fmaf(dx, dx, dy * dy));
      float v = SIGMA_SQ * __builtin_amdgcn_exp2f(-d);  // neg -> input modifier
      if (c % ROWS == rr) v += tdiag[c / ROWS];
      a[rr][c] = v;
    }
  }

  // 20 explicit template steps: compile-time K everywhere.
  __builtin_amdgcn_s_setprio(1);
  gj_step<0>(a, o, ofl);  gj_step<1>(a, o, ofl);  gj_step<2>(a, o, ofl);
  gj_step<3>(a, o, ofl);  gj_step<4>(a, o, ofl);  gj_step<5>(a, o, ofl);
  gj_step<6>(a, o, ofl);  gj_step<7>(a, o, ofl);  gj_step<8>(a, o, ofl);
  gj_step<9>(a, o, ofl);  gj_step<10>(a, o, ofl); gj_step<11>(a, o, ofl);
  gj_step<12>(a, o, ofl); gj_step<13>(a, o, ofl); gj_step<14>(a, o, ofl);
  gj_step<15>(a, o, ofl); gj_step<16>(a, o, ofl); gj_step<17>(a, o, ofl);
  gj_step<18>(a, o, ofl); gj_step<19>(a, o, ofl);
  __builtin_amdgcn_s_setprio(0);

  // SYMMETRY EPILOGUE: C = A^-1 is symmetric, so lane o's a[rr][c] =
  // C[5o+rr][c] = C[c][5o+rr] -- write it as COLUMNS 5o..5o+4 of the
  // row-major output. Per output row c, the quad's four lanes cover the
  // full 80 B densely (float4 at 5o, scalar at 5o+4), adjacent instructions
  // complete each sector within the write-combine window. No LDS, no fences.
  if (m < B) {
    float* om = out + (size_t)m * (N * N) + 5 * o;
#pragma unroll
    for (int c = 0; c < N; ++c) {
      *(float4*)&om[c * N] =
          make_float4(a[0][c], a[1][c], a[2][c], a[3][c]);
      om[c * N + 4] = a[4][c];
    }
  }
}

}  // namespace

extern "C" void kernel_launch(void* const* d_in, const int* in_sizes, int n_in,
                              void* d_out, int out_size, void* d_ws, size_t ws_size,
                              hipStream_t stream) {
  const float* pos = (const float*)d_in[0];   // [B, 40] f32
  // d_in[1] (edge_list, int64) is unused by the reference computation.
  float* out = (float*)d_out;                 // [B, 20, 20] f32
  const int B = in_sizes[0] / (2 * N);
  const int blocks = (B + MATS_PER_BLOCK - 1) / MATS_PER_BLOCK;
  invcov_kernel<<<blocks, 256, 0, stream>>>(pos, out, B);
}

// Round 14
// 85.598 us; speedup vs baseline: 5.4121x; 1.4615x over previous
//
#include <hip/hip_runtime.h>

namespace {

constexpr int N = 20;                  // NEIGHBOR_SIZE
constexpr int ROWS = 5;                // rows per lane
constexpr int NP = N / 2;              // 10 column-pairs per row
constexpr int GROUPS = 16;             // 4-lane quads per wave = 16 matrices/wave
constexpr int WAVES_PER_BLOCK = 4;     // 256 threads
constexpr int MATS_PER_BLOCK = GROUPS * WAVES_PER_BLOCK;  // 64 -> 3125 blocks
constexpr float SIGMA_SQ = 1.0f;
constexpr float PHI = 0.5f;
constexpr float TAU = 0.1f;
constexpr float CSCALE = 0.72134752f;  // PHI * log2(e)

typedef float f32x2 __attribute__((ext_vector_type(2)));

// Broadcast lane SRC of each 4-lane quad to all 4 lanes: DPP quad_perm.
template <int SRC>
__device__ __forceinline__ float qbcast(float x) {
  constexpr int CTRL = SRC * 0x55;
  return __builtin_bit_cast(
      float, __builtin_amdgcn_mov_dpp(__builtin_bit_cast(int, x), CTRL, 0xF,
                                      0xF, true));
}

// One Gauss-Jordan step on the PACKED tableau a2[5][10] (f32x2 pairs ->
// v_pk_fma_f32, 2 FLOP/inst). K template => every index compile-time.
template <int K>
__device__ __forceinline__ void gj_step(f32x2 (&a2)[ROWS][NP], int o,
                                        const float (&ofl)[4]) {
  constexpr int KO = K / ROWS;         // owner lane of row K
  constexpr int KR = K % ROWS;         // owner-local row index
  constexpr int KP = K / 2;            // column-pair of K
  constexpr int KE = K % 2;            // element within pair

  f32x2 r2[NP];
#pragma unroll
  for (int q = 0; q < NP; ++q) {
    r2[q].x = qbcast<KO>(a2[KR][q].x);
    r2[q].y = qbcast<KO>(a2[KR][q].y);
  }
  const float rK = KE ? r2[KP].y : r2[KP].x;
  const float ip = __builtin_amdgcn_rcpf(rK);
  const float fpiv = 1.0f - ip;

#pragma unroll
  for (int rr = 0; rr < ROWS; ++rr) {
    const float aK = KE ? a2[rr][KP].y : a2[rr][KP].x;
    float f = aK * ip;
    if (rr == KR) f = (o == KO) ? fpiv : f;  // one cndmask, only on row KR
    const float nf = -f;
    const f32x2 nf2 = {nf, nf};
    // 10 pk-FMAs; element K's pair computes a garbage lane, fixed below.
#pragma unroll
    for (int q = 0; q < NP; ++q) {
      a2[rr][q] = __builtin_elementwise_fma(nf2, r2[q], a2[rr][q]);
    }
    if (KE) a2[rr][KP].y = nf; else a2[rr][KP].x = nf;  // col K: -A[i][K]/p
  }
  // owner diag: (1/p - 1) + 1 = 1/p
  if (KE) a2[KR][KP].y += ofl[KO]; else a2[KR][KP].x += ofl[KO];
}

__global__ __launch_bounds__(256, 2) void invcov_kernel(
    const float* __restrict__ pos, float* __restrict__ out, int B) {
  // Per-wave 6.4 KB transpose buffer (4 matrices x 400 floats), 4 passes.
  // Wave-local only -> lgkmcnt fences (R7 lesson: fences ARE required).
  __shared__ float lds[WAVES_PER_BLOCK][4 * N * N];

  const int tid  = threadIdx.x;
  const int lane = tid & 63;
  const int wave = tid >> 6;
  const int g    = lane >> 2;          // quad = matrix within wave, 0..15
  const int o    = lane & 3;           // lane within quad, owns rows 5o..5o+4
  const int mwave0 = blockIdx.x * MATS_PER_BLOCK + wave * GROUPS;
  const int m    = mwave0 + g;
  const int mc   = (m < B) ? m : (B - 1);

  const float* pm = pos + (size_t)mc * (2 * N);

  // 20 points in registers as column-PAIRS, pre-scaled by CSCALE.
  f32x2 px2[NP], py2[NP];
  {
    const float4* pv = (const float4*)pm;
#pragma unroll
    for (int q = 0; q < NP; ++q) {
      const float4 p = pv[q];              // cols 2q (x,y) and 2q+1 (z,w)
      px2[q].x = p.x * CSCALE; px2[q].y = p.z * CSCALE;
      py2[q].x = p.y * CSCALE; py2[q].y = p.w * CSCALE;
    }
  }
  // My 5 rows' coords: runtime offset -> tiny L1-hit loads, no reg-indexing.
  float myx[ROWS], myy[ROWS];
  {
    const float2* pm2 = (const float2*)pm;
#pragma unroll
    for (int rr = 0; rr < ROWS; ++rr) {
      const float2 p = pm2[ROWS * o + rr];
      myx[rr] = p.x * CSCALE; myy[rr] = p.y * CSCALE;
    }
  }

  // Per-quad-lane constant masks, constant-indexed.
  float tdiag[4], ofl[4];
#pragma unroll
  for (int t = 0; t < 4; ++t) {
    const bool is = (o == t);
    tdiag[t] = is ? (TAU * SIGMA_SQ) : 0.0f;
    ofl[t]   = is ? 1.0f : 0.0f;
  }

  // Build my 5 rows (packed pairs): a = s^2 * 2^(-C*d) (+ tau*s^2 on diag).
  f32x2 a2[ROWS][NP];
#pragma unroll
  for (int rr = 0; rr < ROWS; ++rr) {
    const f32x2 mx = {myx[rr], myx[rr]};
    const f32x2 my = {myy[rr], myy[rr]};
#pragma unroll
    for (int q = 0; q < NP; ++q) {
      const f32x2 dx = px2[q] - mx;        // v_pk_add (neg mod)
      const f32x2 dy = py2[q] - my;
      f32x2 s = dx * dx;                   // v_pk_mul
      s = __builtin_elementwise_fma(dy, dy, s);  // v_pk_fma
      const float d0 = __builtin_amdgcn_sqrtf(s.x);
      const float d1 = __builtin_amdgcn_sqrtf(s.y);
      float v0 = SIGMA_SQ * __builtin_amdgcn_exp2f(-d0);
      float v1 = SIGMA_SQ * __builtin_amdgcn_exp2f(-d1);
      if ((2 * q) % ROWS == rr)     v0 += tdiag[(2 * q) / ROWS];
      if ((2 * q + 1) % ROWS == rr) v1 += tdiag[(2 * q + 1) / ROWS];
      a2[rr][q].x = v0; a2[rr][q].y = v1;
    }
  }

  // 20 explicit template steps: compile-time K everywhere.
  __builtin_amdgcn_s_setprio(1);
  gj_step<0>(a2, o, ofl);  gj_step<1>(a2, o, ofl);  gj_step<2>(a2, o, ofl);
  gj_step<3>(a2, o, ofl);  gj_step<4>(a2, o, ofl);  gj_step<5>(a2, o, ofl);
  gj_step<6>(a2, o, ofl);  gj_step<7>(a2, o, ofl);  gj_step<8>(a2, o, ofl);
  gj_step<9>(a2, o, ofl);  gj_step<10>(a2, o, ofl); gj_step<11>(a2, o, ofl);
  gj_step<12>(a2, o, ofl); gj_step<13>(a2, o, ofl); gj_step<14>(a2, o, ofl);
  gj_step<15>(a2, o, ofl); gj_step<16>(a2, o, ofl); gj_step<17>(a2, o, ofl);
  gj_step<18>(a2, o, ofl); gj_step<19>(a2, o, ofl);
  __builtin_amdgcn_s_setprio(0);

  float* wbuf = &lds[wave][0];

  if (mwave0 + GROUPS <= B) {
    // Dense epilogue (R8-identical): 4 passes of 4 matrices via LDS.
#pragma unroll
    for (int p = 0; p < 4; ++p) {
      if ((g >> 2) == p) {
        float* dst = wbuf + (g & 3) * (N * N) + o * (ROWS * N);
#pragma unroll
        for (int rr = 0; rr < ROWS; ++rr) {
#pragma unroll
          for (int q = 0; q < N / 4; ++q) {   // float4 = pairs 2q, 2q+1
            *(float4*)&dst[rr * N + 4 * q] =
                make_float4(a2[rr][2 * q].x, a2[rr][2 * q].y,
                            a2[rr][2 * q + 1].x, a2[rr][2 * q + 1].y);
          }
        }
      }
      asm volatile("s_waitcnt lgkmcnt(0)" ::: "memory");

      float* gout = out + (size_t)(mwave0 + 4 * p) * (N * N);
#pragma unroll
      for (int s = 0; s < 6; ++s) {
        const float4 v = *(const float4*)&wbuf[lane * 4 + s * 256];
        *(float4*)&gout[lane * 4 + s * 256] = v;
      }
      if (lane < 16) {
        const float4 v = *(const float4*)&wbuf[lane * 4 + 6 * 256];
        *(float4*)&gout[lane * 4 + 6 * 256] = v;
      }
      // Reads must land in VGPRs before next pass overwrites the buffer.
      asm volatile("s_waitcnt lgkmcnt(0)" ::: "memory");
    }
  } else if (m < B) {
    // Rare tail wave: direct (slow) per-lane stores.
    float* om = out + (size_t)m * (N * N) + (ROWS * o) * N;
#pragma unroll
    for (int rr = 0; rr < ROWS; ++rr) {
#pragma unroll
      for (int q = 0; q < N / 4; ++q) {
        *(float4*)&om[rr * N + 4 * q] =
            make_float4(a2[rr][2 * q].x, a2[rr][2 * q].y,
                        a2[rr][2 * q + 1].x, a2[rr][2 * q + 1].y);
      }
    }
  }
}

}  // namespace

extern "C" void kernel_launch(void* const* d_in, const int* in_sizes, int n_in,
                              void* d_out, int out_size, void* d_ws, size_t ws_size,
                              hipStream_t stream) {
  const float* pos = (const float*)d_in[0];   // [B, 40] f32
  // d_in[1] (edge_list, int64) is unused by the reference computation.
  float* out = (float*)d_out;                 // [B, 20, 20] f32
  const int B = in_sizes[0] / (2 * N);
  const int blocks = (B + MATS_PER_BLOCK - 1) / MATS_PER_BLOCK;
  invcov_kernel<<<blocks, 256, 0, stream>>>(pos, out, B);
}